// Round 3
// baseline (1163.210 us; speedup 1.0000x reference)
//
#include <hip/hip_runtime.h>

#define T 8192
#define D 1024
#define E 64
#define CAP 256

typedef float f32x4 __attribute__((ext_vector_type(4)));  // clang-native vec (nontemporal-store ok)

static const size_t TEC = (size_t)T * E * CAP;       // 134217728
#define C_OFF   ((size_t)1)
#define M_OFF   ((size_t)1 + (size_t)T * E * CAP)
#define CNT_OFF ((size_t)1 + 2 * (size_t)T * E * CAP)

// K1: one wave per token. red = x_row @ W_red (wave-reduced), logits vs
// normalized centroids (lane = expert), softmax + first-index argmax.
// Accumulates Sg[e] partials -> global atomics, and the per-256-token-chunk
// expert histogram bc[chunk][e] directly (one atomicAdd per token; bc must
// be pre-zeroed). Replaces the old separate k2_hist pass.
__global__ __launch_bounds__(256) void k1_gate(
    const float* __restrict__ x, const float* __restrict__ Wred,
    const float* __restrict__ cent, int* __restrict__ idx1,
    float* __restrict__ g15, float* __restrict__ Sg, int* __restrict__ bc)
{
    __shared__ float wcol[4 * D];   // column-major: wcol[c*D + d], bank = d%32 (2-way, free)
    __shared__ float cn[E * 4];
    __shared__ float sg[E];
    const int tid = threadIdx.x;

    for (int i = tid; i < 4 * D; i += 256) {
        int d = i >> 2, c = i & 3;
        wcol[c * D + d] = Wred[i];
    }
    if (tid < E) {
        float c0 = cent[tid * 4 + 0];
        float c1 = cent[tid * 4 + 1];
        float c2 = cent[tid * 4 + 2];
        float c3 = cent[tid * 4 + 3];
        float n = fmaxf(sqrtf(c0 * c0 + c1 * c1 + c2 * c2 + c3 * c3), 1e-4f);
        cn[tid * 4 + 0] = c0 / n;
        cn[tid * 4 + 1] = c1 / n;
        cn[tid * 4 + 2] = c2 / n;
        cn[tid * 4 + 3] = c3 / n;
        sg[tid] = 0.0f;
    }
    __syncthreads();

    const int wave = tid >> 6, lane = tid & 63;
    for (int it = 0; it < 4; ++it) {               // 512 blocks * 4 iters * 4 waves = 8192 tokens
        const int t = blockIdx.x * 16 + it * 4 + wave;
        const float* xr = x + (size_t)t * D;
        float a0 = 0.f, a1 = 0.f, a2 = 0.f, a3 = 0.f;
        #pragma unroll
        for (int k = 0; k < 16; ++k) {
            int d = k * 64 + lane;                 // coalesced 4B/lane
            float xv = xr[d];
            a0 += xv * wcol[d];
            a1 += xv * wcol[D + d];
            a2 += xv * wcol[2 * D + d];
            a3 += xv * wcol[3 * D + d];
        }
        #pragma unroll
        for (int off = 32; off; off >>= 1) {       // xor-butterfly: all lanes get full sums
            a0 += __shfl_xor(a0, off);
            a1 += __shfl_xor(a1, off);
            a2 += __shfl_xor(a2, off);
            a3 += __shfl_xor(a3, off);
        }
        // lane e's logit = red . cn[e]
        float logit = a0 * cn[lane * 4 + 0] + a1 * cn[lane * 4 + 1]
                    + a2 * cn[lane * 4 + 2] + a3 * cn[lane * 4 + 3];
        float m = logit;
        #pragma unroll
        for (int off = 32; off; off >>= 1) m = fmaxf(m, __shfl_xor(m, off));
        unsigned long long ball = __ballot(logit == m);
        int amax = __ffsll(ball) - 1;              // first-occurrence argmax (matches jnp)
        float ev = expf(logit - m);
        float s = ev;
        #pragma unroll
        for (int off = 32; off; off >>= 1) s += __shfl_xor(s, off);
        atomicAdd(&sg[lane], ev / s);              // Sg partial, distinct addr per lane
        if (lane == 0) {
            idx1[t] = amax;
            g15[t] = 1.5f / s;                     // gate at argmax = 1/s
            atomicAdd(&bc[(t >> 8) * E + amax], 1); // chunk histogram (fused k2)
        }
    }
    __syncthreads();
    if (tid < E) atomicAdd(&Sg[tid], sg[tid]);
}

// K3: one wave. Exclusive prefix over chunks per expert, total counts,
// l_aux = E * sum_e Sg[e]*cnt[e] / T^2. Also writes out[0] and the
// expert_counts tail (the only output floats not covered by k4).
__global__ __launch_bounds__(64) void k3_prefix(const int* __restrict__ bc,
                                                int* __restrict__ pf,
                                                const float* __restrict__ Sg,
                                                float* __restrict__ out)
{
    const int e = threadIdx.x;   // 64 threads = 64 experts
    int run = 0;
    for (int b = 0; b < 32; ++b) {
        pf[b * E + e] = run;
        run += bc[b * E + e];
    }
    out[CNT_OFF + e] = (float)run;                 // expert_counts (pre-capacity)
    float v = Sg[e] * (float)run;
    #pragma unroll
    for (int off = 32; off; off >>= 1) v += __shfl_xor(v, off);
    if (e == 0) out[0] = v * ((float)E / ((float)T * (float)T));  // 64/2^26 exact
}

// K4: fused zero + rank + scatter. One block per token. Writes the token's
// combine row (16384 floats) and mask row (16384 floats) as nontemporal
// float4 zeros, then patches the single nonzero slot. Replaces the 1.07-GB
// hipMemsetAsync AND the old k4 scatter: the output region is written
// exactly once. Rank is computed with a ballot/popc block reduce instead
// of the old 256-iteration serial scan.
// Alignment: rows start at float index t*16384 + 1 (C_OFF=1, M_OFF%4=1),
// so the 16B-aligned body is [base+3, base+3+4*4095) with 3 head + 1 tail
// scalar floats.
__global__ __launch_bounds__(256) void k4_fill_scatter(
    const int* __restrict__ idx1, const float* __restrict__ g15,
    const int* __restrict__ pf, float* __restrict__ out)
{
    const int tid = threadIdx.x;
    const int t = blockIdx.x;
    const int chunk = t >> 8;
    const int tin = t & 255;

    __shared__ int ids[256];
    __shared__ int wsum[4];
    const int e = idx1[t];
    ids[tid] = idx1[chunk * 256 + tid];
    __syncthreads();
    // rank within chunk: |{ j < tin : ids[j] == e }| via per-wave ballot
    int flag = (tid < tin && ids[tid] == e) ? 1 : 0;
    unsigned long long b = __ballot(flag != 0);
    if ((tid & 63) == 0) wsum[tid >> 6] = __popcll(b);
    __syncthreads();
    const int rank = pf[chunk * E + e] + wsum[0] + wsum[1] + wsum[2] + wsum[3];

    float* __restrict__ crow = out + C_OFF + (size_t)t * (E * CAP);
    float* __restrict__ mrow = out + M_OFF + (size_t)t * (E * CAP);
    const f32x4 z4 = {0.f, 0.f, 0.f, 0.f};
    #pragma unroll
    for (int k = 0; k < 16; ++k) {
        int i = tid + k * 256;
        if (i < 4095) {
            __builtin_nontemporal_store(z4, (f32x4*)(crow + 3 + 4 * (size_t)i));
            __builtin_nontemporal_store(z4, (f32x4*)(mrow + 3 + 4 * (size_t)i));
        }
    }
    if (tid == 0) {
        crow[0] = 0.f; crow[1] = 0.f; crow[2] = 0.f; crow[16383] = 0.f;
        mrow[0] = 0.f; mrow[1] = 0.f; mrow[2] = 0.f; mrow[16383] = 0.f;
    }
    __syncthreads();                               // drains vmcnt before patch
    if (tid == 0 && rank < CAP) {
        size_t o = (size_t)e * CAP + rank;
        crow[o] = g15[t];                          // combine value (1.5 * max gate, > 0)
        mrow[o] = 1.0f;                            // dispatch_mask
    }
}

extern "C" void kernel_launch(void* const* d_in, const int* in_sizes, int n_in,
                              void* d_out, int out_size, void* d_ws, size_t ws_size,
                              hipStream_t stream)
{
    const float* x    = (const float*)d_in[0];   // [T, D]
    const float* Wred = (const float*)d_in[1];   // [D, 4]
    const float* cent = (const float*)d_in[2];   // [E, 4]
    float* out = (float*)d_out;

    char* ws = (char*)d_ws;                      // ~82 KB used
    int*   idx1 = (int*)ws;                      // T ints
    float* g15  = (float*)(ws + 32768);          // T floats
    float* Sg   = (float*)(ws + 65536);          // 64 floats   (zeroed)
    int*   bc   = (int*)(ws + 65536 + 256);      // 32*64 ints  (zeroed, k1 accumulates)
    int*   pf   = (int*)(ws + 65536 + 256 + 8192);

    // Only workspace accumulators need zeroing (8.4 KB). The 1.074-GB output
    // is written exactly once by k4_fill_scatter (zeros + nonzero patches);
    // out[0] and the counts tail are written by k3.
    (void)hipMemsetAsync(Sg, 0, 256 + 32 * E * sizeof(int), stream);

    k1_gate<<<512, 256, 0, stream>>>(x, Wred, cent, idx1, g15, Sg, bc);
    k3_prefix<<<1, 64, 0, stream>>>(bc, pf, Sg, out);
    k4_fill_scatter<<<T, 256, 0, stream>>>(idx1, g15, pf, out);
}

// Round 4
// 1092.750 us; speedup vs baseline: 1.0645x; 1.0645x over previous
//
#include <hip/hip_runtime.h>

#define T 8192
#define D 1024
#define E 64
#define CAP 256

typedef float f32x4 __attribute__((ext_vector_type(4)));

#define TEC ((size_t)134217728)            // T*E*CAP
#define C_OFF   ((size_t)1)
#define M_OFF   ((size_t)1 + TEC)
#define CNT_OFF ((size_t)1 + 2 * TEC)

// kA: gate + zero-fill fused. 2048 blocks x 256. Each block gates 4 tokens
// (one per wave) exactly as the verified k1, then zero-fills a contiguous
// 512-KB slice of the combine+mask region with PLAIN float4 stores
// (no nontemporal, no drain — R3 showed nt + per-block vmcnt(0) drain ran
// at 2.5 TB/s vs rocclr fill's 6.2 TB/s). Fill has no dependency on the
// gate results, so store issue overlaps gate compute freely.
__global__ __launch_bounds__(256) void kA_gate_fill(
    const float* __restrict__ x, const float* __restrict__ Wred,
    const float* __restrict__ cent, int* __restrict__ idx1,
    float* __restrict__ g15, float* __restrict__ Sg, int* __restrict__ bc,
    float* __restrict__ out)
{
    __shared__ float wcol[4 * D];   // column-major: wcol[c*D + d]
    __shared__ float cn[E * 4];
    __shared__ float sg[E];
    const int tid = threadIdx.x;

    for (int i = tid; i < 4 * D; i += 256) {
        int d = i >> 2, c = i & 3;
        wcol[c * D + d] = Wred[i];
    }
    if (tid < E) {
        float c0 = cent[tid * 4 + 0];
        float c1 = cent[tid * 4 + 1];
        float c2 = cent[tid * 4 + 2];
        float c3 = cent[tid * 4 + 3];
        float n = fmaxf(sqrtf(c0 * c0 + c1 * c1 + c2 * c2 + c3 * c3), 1e-4f);
        cn[tid * 4 + 0] = c0 / n;
        cn[tid * 4 + 1] = c1 / n;
        cn[tid * 4 + 2] = c2 / n;
        cn[tid * 4 + 3] = c3 / n;
        sg[tid] = 0.0f;
    }
    __syncthreads();

    const int wave = tid >> 6, lane = tid & 63;
    const int t = blockIdx.x * 4 + wave;           // 2048 blocks * 4 waves = 8192 tokens
    {
        const float* xr = x + (size_t)t * D;
        float a0 = 0.f, a1 = 0.f, a2 = 0.f, a3 = 0.f;
        #pragma unroll
        for (int k = 0; k < 16; ++k) {
            int d = k * 64 + lane;                 // coalesced 4B/lane
            float xv = xr[d];
            a0 += xv * wcol[d];
            a1 += xv * wcol[D + d];
            a2 += xv * wcol[2 * D + d];
            a3 += xv * wcol[3 * D + d];
        }
        #pragma unroll
        for (int off = 32; off; off >>= 1) {       // xor-butterfly: all lanes get full sums
            a0 += __shfl_xor(a0, off);
            a1 += __shfl_xor(a1, off);
            a2 += __shfl_xor(a2, off);
            a3 += __shfl_xor(a3, off);
        }
        float logit = a0 * cn[lane * 4 + 0] + a1 * cn[lane * 4 + 1]
                    + a2 * cn[lane * 4 + 2] + a3 * cn[lane * 4 + 3];
        float m = logit;
        #pragma unroll
        for (int off = 32; off; off >>= 1) m = fmaxf(m, __shfl_xor(m, off));
        unsigned long long ball = __ballot(logit == m);
        int amax = __ffsll(ball) - 1;              // first-occurrence argmax (matches jnp)
        float ev = expf(logit - m);
        float s = ev;
        #pragma unroll
        for (int off = 32; off; off >>= 1) s += __shfl_xor(s, off);
        atomicAdd(&sg[lane], ev / s);              // Sg partial, distinct addr per lane
        if (lane == 0) {
            idx1[t] = amax;
            g15[t] = 1.5f / s;                     // gate at argmax = 1/s
            atomicAdd(&bc[(t >> 8) * E + amax], 1); // chunk histogram
        }
    }
    __syncthreads();
    if (tid < E) atomicAdd(&Sg[tid], sg[tid]);

    // ---- zero-fill: floats [1, 2*TEC+1) of out. Aligned bulk [4, 2*TEC)
    // = 67108863 float4s; 2048 blocks x 32768 float4 contiguous slices.
    const f32x4 z4 = {0.f, 0.f, 0.f, 0.f};
    f32x4* __restrict__ base = (f32x4*)(out + 4);
    const size_t b0 = (size_t)blockIdx.x * 32768;
    #pragma unroll 4
    for (int k = 0; k < 128; ++k) {
        size_t fi = b0 + (size_t)k * 256 + tid;
        if (fi < (size_t)67108863) base[fi] = z4;  // plain store, fire-and-forget
    }
    if (blockIdx.x == 0 && tid < 4) {              // scalar head 1..3, tail 2*TEC
        if (tid < 3) out[1 + tid] = 0.f;
        else         out[2 * TEC] = 0.f;
    }
}

// k5: per-chunk prefix + rank + patch. 32 blocks x 256 (block = 256-token
// chunk). pf computed inline from bc (k3 deleted). Within-chunk rank via
// expert-bit ballot matching (6 ballots) + cross-wave LDS counts. Block 31
// additionally writes expert_counts and l_aux (it owns the full prefix).
__global__ __launch_bounds__(256) void k5_prefix_patch(
    const int* __restrict__ idx1, const float* __restrict__ g15,
    const int* __restrict__ bc, const float* __restrict__ Sg,
    float* __restrict__ out)
{
    __shared__ int pfe[E];
    __shared__ int cwf[256];                       // cwf[w*64+e]: count of e in wave w
    const int tid = threadIdx.x;
    const int chunk = blockIdx.x;
    const int t = chunk * 256 + tid;
    const int e = idx1[t];

    if (tid < E) {
        int run = 0;
        for (int b = 0; b < chunk; ++b) run += bc[b * E + tid];
        pfe[tid] = run;                            // tokens of expert `tid` in earlier chunks
    }
    cwf[tid] = 0;
    __syncthreads();

    const int wave = tid >> 6, lane = tid & 63;
    unsigned long long same = ~0ull;               // lanes in my wave with same expert
    #pragma unroll
    for (int b = 0; b < 6; ++b) {
        unsigned long long bal = __ballot(((e >> b) & 1) != 0);
        same &= ((e >> b) & 1) ? bal : ~bal;
    }
    const unsigned long long below = ((unsigned long long)1 << lane) - 1ull;
    const int rank_in_wave = __popcll(same & below);
    if ((same & below) == 0ull) cwf[wave * E + e] = __popcll(same);  // wave leader
    __syncthreads();

    int rank = pfe[e] + rank_in_wave;
    if (wave > 0) rank += cwf[0 * E + e];
    if (wave > 1) rank += cwf[1 * E + e];
    if (wave > 2) rank += cwf[2 * E + e];

    if (rank < CAP) {
        const size_t row = (size_t)t * (E * CAP) + (size_t)e * CAP + rank;
        out[C_OFF + row] = g15[t];                 // combine value (1.5 * max gate, > 0)
        out[M_OFF + row] = 1.0f;                   // dispatch_mask
    }

    if (chunk == 31 && tid < E) {                  // totals, counts, l_aux
        int total = pfe[tid] + bc[31 * E + tid];
        out[CNT_OFF + tid] = (float)total;         // expert_counts (pre-capacity)
        float v = Sg[tid] * (float)total;
        #pragma unroll
        for (int off = 32; off; off >>= 1) v += __shfl_xor(v, off);
        if (tid == 0) out[0] = v * ((float)E / ((float)T * (float)T));  // 64/2^26 exact
    }
}

extern "C" void kernel_launch(void* const* d_in, const int* in_sizes, int n_in,
                              void* d_out, int out_size, void* d_ws, size_t ws_size,
                              hipStream_t stream)
{
    const float* x    = (const float*)d_in[0];   // [T, D]
    const float* Wred = (const float*)d_in[1];   // [D, 4]
    const float* cent = (const float*)d_in[2];   // [E, 4]
    float* out = (float*)d_out;

    char* ws = (char*)d_ws;
    int*   idx1 = (int*)ws;                      // T ints
    float* g15  = (float*)(ws + 32768);          // T floats
    float* Sg   = (float*)(ws + 65536);          // 64 floats   (zeroed)
    int*   bc   = (int*)(ws + 65536 + 256);      // 32*64 ints  (zeroed, kA accumulates)

    // Only workspace accumulators need zeroing (8.4 KB). The 1.074-GB output
    // is written exactly once: kA zero-fills with plain float4 stores,
    // k5 patches the nonzeros and writes out[0] + counts.
    (void)hipMemsetAsync(Sg, 0, 256 + 32 * E * sizeof(int), stream);

    kA_gate_fill<<<2048, 256, 0, stream>>>(x, Wred, cent, idx1, g15, Sg, bc, out);
    k5_prefix_patch<<<32, 256, 0, stream>>>(idx1, g15, bc, Sg, out);
}

// Round 5
// 932.122 us; speedup vs baseline: 1.2479x; 1.1723x over previous
//
#include <hip/hip_runtime.h>

#define T 8192
#define D 1024
#define E 64
#define CAP 256

typedef float f32x4 __attribute__((ext_vector_type(4)));

#define TEC ((size_t)134217728)            // T*E*CAP
#define C_OFF   ((size_t)1)
#define M_OFF   ((size_t)1 + TEC)
#define CNT_OFF ((size_t)1 + 2 * TEC)

// K1: one wave per token (512 blocks x 16 tokens — R1's proven shape).
// red = x_row @ W_red with f32x4 global loads (16B/lane) and ds_read_b128
// LDS reads; logits vs normalized centroids (lane = expert), softmax +
// first-index argmax. Fuses the per-chunk expert histogram (bc) that used
// to be k2 (one atomicAdd per token; bc pre-zeroed).
__global__ __launch_bounds__(256) void k1_gate(
    const float* __restrict__ x, const float* __restrict__ Wred,
    const float* __restrict__ cent, int* __restrict__ idx1,
    float* __restrict__ g15, float* __restrict__ Sg, int* __restrict__ bc)
{
    __shared__ float wcol[4 * D];   // column-major: wcol[c*D + d]
    __shared__ float cn[E * 4];
    __shared__ float sg[E];
    const int tid = threadIdx.x;

    for (int i = tid; i < 4 * D; i += 256) {
        int d = i >> 2, c = i & 3;
        wcol[c * D + d] = Wred[i];
    }
    if (tid < E) {
        float c0 = cent[tid * 4 + 0];
        float c1 = cent[tid * 4 + 1];
        float c2 = cent[tid * 4 + 2];
        float c3 = cent[tid * 4 + 3];
        float n = fmaxf(sqrtf(c0 * c0 + c1 * c1 + c2 * c2 + c3 * c3), 1e-4f);
        cn[tid * 4 + 0] = c0 / n;
        cn[tid * 4 + 1] = c1 / n;
        cn[tid * 4 + 2] = c2 / n;
        cn[tid * 4 + 3] = c3 / n;
        sg[tid] = 0.0f;
    }
    __syncthreads();

    const f32x4* __restrict__ wc4 = (const f32x4*)wcol;   // [4][256] f32x4
    const int wave = tid >> 6, lane = tid & 63;
    for (int it = 0; it < 4; ++it) {               // 512 blocks * 4 iters * 4 waves = 8192 tokens
        const int t = blockIdx.x * 16 + it * 4 + wave;
        const f32x4* __restrict__ xr4 = (const f32x4*)(x + (size_t)t * D);
        float a0 = 0.f, a1 = 0.f, a2 = 0.f, a3 = 0.f;
        #pragma unroll
        for (int k = 0; k < 4; ++k) {
            const int i = k * 64 + lane;           // f32x4 index: 16B/lane, coalesced
            const f32x4 xv = xr4[i];
            const f32x4 w0 = wc4[0 * 256 + i];
            const f32x4 w1 = wc4[1 * 256 + i];
            const f32x4 w2 = wc4[2 * 256 + i];
            const f32x4 w3 = wc4[3 * 256 + i];
            a0 += xv[0] * w0[0] + xv[1] * w0[1] + xv[2] * w0[2] + xv[3] * w0[3];
            a1 += xv[0] * w1[0] + xv[1] * w1[1] + xv[2] * w1[2] + xv[3] * w1[3];
            a2 += xv[0] * w2[0] + xv[1] * w2[1] + xv[2] * w2[2] + xv[3] * w2[3];
            a3 += xv[0] * w3[0] + xv[1] * w3[1] + xv[2] * w3[2] + xv[3] * w3[3];
        }
        #pragma unroll
        for (int off = 32; off; off >>= 1) {       // xor-butterfly: all lanes get full sums
            a0 += __shfl_xor(a0, off);
            a1 += __shfl_xor(a1, off);
            a2 += __shfl_xor(a2, off);
            a3 += __shfl_xor(a3, off);
        }
        float logit = a0 * cn[lane * 4 + 0] + a1 * cn[lane * 4 + 1]
                    + a2 * cn[lane * 4 + 2] + a3 * cn[lane * 4 + 3];
        float m = logit;
        #pragma unroll
        for (int off = 32; off; off >>= 1) m = fmaxf(m, __shfl_xor(m, off));
        unsigned long long ball = __ballot(logit == m);
        int amax = __ffsll(ball) - 1;              // first-occurrence argmax (matches jnp)
        float ev = expf(logit - m);
        float s = ev;
        #pragma unroll
        for (int off = 32; off; off >>= 1) s += __shfl_xor(s, off);
        atomicAdd(&sg[lane], ev / s);              // Sg partial, distinct addr per lane
        if (lane == 0) {
            idx1[t] = amax;
            g15[t] = 1.5f / s;                     // gate at argmax = 1/s
            atomicAdd(&bc[(t >> 8) * E + amax], 1); // chunk histogram (fused k2)
        }
    }
    __syncthreads();
    if (tid < E) atomicAdd(&Sg[tid], sg[tid]);
}

// k5: per-chunk prefix + rank + patch (verified in R4). 32 blocks x 256
// (block = 256-token chunk). pf computed inline from bc. Within-chunk rank
// via expert-bit ballot matching (6 ballots) + cross-wave LDS counts.
// Block 31 additionally writes expert_counts and l_aux.
__global__ __launch_bounds__(256) void k5_prefix_patch(
    const int* __restrict__ idx1, const float* __restrict__ g15,
    const int* __restrict__ bc, const float* __restrict__ Sg,
    float* __restrict__ out)
{
    __shared__ int pfe[E];
    __shared__ int cwf[256];                       // cwf[w*64+e]: count of e in wave w
    const int tid = threadIdx.x;
    const int chunk = blockIdx.x;
    const int t = chunk * 256 + tid;
    const int e = idx1[t];

    if (tid < E) {
        int run = 0;
        for (int b = 0; b < chunk; ++b) run += bc[b * E + tid];
        pfe[tid] = run;                            // tokens of expert `tid` in earlier chunks
    }
    cwf[tid] = 0;
    __syncthreads();

    const int wave = tid >> 6, lane = tid & 63;
    unsigned long long same = ~0ull;               // lanes in my wave with same expert
    #pragma unroll
    for (int b = 0; b < 6; ++b) {
        unsigned long long bal = __ballot(((e >> b) & 1) != 0);
        same &= ((e >> b) & 1) ? bal : ~bal;
    }
    const unsigned long long below = ((unsigned long long)1 << lane) - 1ull;
    const int rank_in_wave = __popcll(same & below);
    if ((same & below) == 0ull) cwf[wave * E + e] = __popcll(same);  // wave leader
    __syncthreads();

    int rank = pfe[e] + rank_in_wave;
    if (wave > 0) rank += cwf[0 * E + e];
    if (wave > 1) rank += cwf[1 * E + e];
    if (wave > 2) rank += cwf[2 * E + e];

    if (rank < CAP) {
        const size_t row = (size_t)t * (E * CAP) + (size_t)e * CAP + rank;
        out[C_OFF + row] = g15[t];                 // combine value (1.5 * max gate, > 0)
        out[M_OFF + row] = 1.0f;                   // dispatch_mask
    }

    if (chunk == 31 && tid < E) {                  // totals, counts, l_aux
        int total = pfe[tid] + bc[31 * E + tid];
        out[CNT_OFF + tid] = (float)total;         // expert_counts (pre-capacity)
        float v = Sg[tid] * (float)total;
        #pragma unroll
        for (int off = 32; off; off >>= 1) v += __shfl_xor(v, off);
        if (tid == 0) out[0] = v * ((float)E / ((float)T * (float)T));  // 64/2^26 exact
    }
}

extern "C" void kernel_launch(void* const* d_in, const int* in_sizes, int n_in,
                              void* d_out, int out_size, void* d_ws, size_t ws_size,
                              hipStream_t stream)
{
    const float* x    = (const float*)d_in[0];   // [T, D]
    const float* Wred = (const float*)d_in[1];   // [D, 4]
    const float* cent = (const float*)d_in[2];   // [E, 4]
    float* out = (float*)d_out;

    char* ws = (char*)d_ws;
    int*   idx1 = (int*)ws;                      // T ints
    float* g15  = (float*)(ws + 32768);          // T floats
    float* Sg   = (float*)(ws + 65536);          // 64 floats   (zeroed)
    int*   bc   = (int*)(ws + 65536 + 256);      // 32*64 ints  (zeroed, k1 accumulates)

    // Output fill via rocclr memset (measured 6.2 TB/s; our compute-kernel
    // fills ran at ~3 TB/s in R3/R4 — reverted). out_size is in BYTES.
    (void)hipMemsetAsync(d_out, 0, (size_t)out_size, stream);
    (void)hipMemsetAsync(Sg, 0, 256 + 32 * E * sizeof(int), stream);

    k1_gate<<<512, 256, 0, stream>>>(x, Wred, cent, idx1, g15, Sg, bc);
    k5_prefix_patch<<<32, 256, 0, stream>>>(idx1, g15, bc, Sg, out);
}